// Round 1
// baseline (443.377 us; speedup 1.0000x reference)
//
#include <hip/hip_runtime.h>

#define CUTOFF 5.0f
#define DEPS 1e-12f

// Workspace accumulator layout (floats):
// 0: ligand coord-loss sum over batches (pre /B)
// 1: ligand dist-loss sum (where has)
// 2: ligand has count
// 3: sidechain mse*am sum
// 4: sidechain am sum
// 5: sidechain dist-loss sum (where has)
// 6: sidechain has count

__global__ __launch_bounds__(256) void ligand_kernel(
    const float* __restrict__ pred, const float* __restrict__ tgt,
    const int* __restrict__ mask, float* __restrict__ acc) {
  const int L = 512;
  const int b = blockIdx.x;
  const int tid = threadIdx.x;

  __shared__ float sp[512 * 3];
  __shared__ float st[512 * 3];
  __shared__ float sm[512];

  const float* pb = pred + (size_t)b * L * 3;
  const float* tb = tgt + (size_t)b * L * 3;
  for (int i = tid; i < L * 3; i += 256) {
    sp[i] = pb[i];
    st[i] = tb[i];
  }
  for (int i = tid; i < L; i += 256) sm[i] = (mask[(size_t)b * L + i] != 0) ? 1.f : 0.f;
  __syncthreads();

  // coord term
  float se = 0.f, cnt = 0.f;
  for (int i = tid; i < L; i += 256) {
    float m = sm[i];
    float dx = sp[i * 3 + 0] - st[i * 3 + 0];
    float dy = sp[i * 3 + 1] - st[i * 3 + 1];
    float dz = sp[i * 3 + 2] - st[i * 3 + 2];
    se += m * (dx * dx + dy * dy + dz * dz);
    cnt += m;
  }

  // pair term, i<j only (num/den ratio and den>0 are invariant under the
  // symmetric halving; diagonal is excluded by tsq>0 anyway)
  float num = 0.f, den = 0.f;
  for (int p = tid; p < L * L; p += 256) {
    int i = p >> 9;
    int j = p & (L - 1);
    if (j <= i) continue;
    if (sm[i] == 0.f || sm[j] == 0.f) continue;
    float tx = st[i * 3 + 0] - st[j * 3 + 0];
    float ty = st[i * 3 + 1] - st[j * 3 + 1];
    float tz = st[i * 3 + 2] - st[j * 3 + 2];
    float tsq = tx * tx + ty * ty + tz * tz;
    if (!(tsq > 0.f)) continue;
    float td = sqrtf(fmaxf(tsq, DEPS));
    if (td > CUTOFF) continue;
    float px = sp[i * 3 + 0] - sp[j * 3 + 0];
    float py = sp[i * 3 + 1] - sp[j * 3 + 1];
    float pz = sp[i * 3 + 2] - sp[j * 3 + 2];
    float psq = px * px + py * py + pz * pz;
    float pd = sqrtf(fmaxf(psq, DEPS));
    float d = pd - td;
    num += d * d;
    den += 1.f;
  }

  // block reduce 4 values
  for (int off = 32; off > 0; off >>= 1) {
    se += __shfl_down(se, off, 64);
    cnt += __shfl_down(cnt, off, 64);
    num += __shfl_down(num, off, 64);
    den += __shfl_down(den, off, 64);
  }
  __shared__ float red[4][4];
  int lane = tid & 63, wave = tid >> 6;
  if (lane == 0) {
    red[0][wave] = se;
    red[1][wave] = cnt;
    red[2][wave] = num;
    red[3][wave] = den;
  }
  __syncthreads();
  if (tid == 0) {
    float se_t = red[0][0] + red[0][1] + red[0][2] + red[0][3];
    float cnt_t = red[1][0] + red[1][1] + red[1][2] + red[1][3];
    float num_t = red[2][0] + red[2][1] + red[2][2] + red[2][3];
    float den_t = red[3][0] + red[3][1] + red[3][2] + red[3][3];
    atomicAdd(&acc[0], se_t / (3.f * fmaxf(cnt_t, 1.f)));
    if (den_t > 0.f) {
      atomicAdd(&acc[1], num_t / fmaxf(den_t, 1.f));
      atomicAdd(&acc[2], 1.f);
    }
  }
}

__global__ __launch_bounds__(256) void sidechain_kernel(
    const float* __restrict__ pred, const float* __restrict__ tgt,
    const int* __restrict__ mask, float* __restrict__ acc) {
  const int A = 14;
  const int g = blockIdx.x * 256 + threadIdx.x;  // 65536 groups (b*1024+r)

  const float* pg = pred + (size_t)g * A * 3;
  const float* tg = tgt + (size_t)g * A * 3;
  const int* mg = mask + (size_t)g * A;

  float px[14], py[14], pz[14], tx[14], ty[14], tz[14], m[14];
  float mse_sum = 0.f, am_sum = 0.f;
#pragma unroll
  for (int a = 0; a < A; a++) {
    px[a] = pg[a * 3 + 0];
    py[a] = pg[a * 3 + 1];
    pz[a] = pg[a * 3 + 2];
    tx[a] = tg[a * 3 + 0];
    ty[a] = tg[a * 3 + 1];
    tz[a] = tg[a * 3 + 2];
    m[a] = (mg[a] != 0) ? 1.f : 0.f;
    float dx = px[a] - tx[a], dy = py[a] - ty[a], dz = pz[a] - tz[a];
    mse_sum += m[a] * ((dx * dx + dy * dy + dz * dz) * (1.f / 3.f));
    am_sum += m[a];
  }

  float num = 0.f, den = 0.f;
#pragma unroll
  for (int i = 0; i < A; i++) {
#pragma unroll
    for (int j = i + 1; j < A; j++) {
      if (m[i] == 0.f || m[j] == 0.f) continue;
      float dx = tx[i] - tx[j], dy = ty[i] - ty[j], dz = tz[i] - tz[j];
      float tsq = dx * dx + dy * dy + dz * dz;
      if (!(tsq > 0.f)) continue;
      float td = sqrtf(fmaxf(tsq, DEPS));
      if (td > CUTOFF) continue;
      float qx = px[i] - px[j], qy = py[i] - py[j], qz = pz[i] - pz[j];
      float pd = sqrtf(fmaxf(qx * qx + qy * qy + qz * qz, DEPS));
      float d = pd - td;
      num += d * d;
      den += 1.f;
    }
  }
  float val = 0.f, has = 0.f;
  if (den > 0.f) {
    val = num / fmaxf(den, 1.f);
    has = 1.f;
  }

  for (int off = 32; off > 0; off >>= 1) {
    mse_sum += __shfl_down(mse_sum, off, 64);
    am_sum += __shfl_down(am_sum, off, 64);
    val += __shfl_down(val, off, 64);
    has += __shfl_down(has, off, 64);
  }
  __shared__ float red[4][4];
  int lane = threadIdx.x & 63, wave = threadIdx.x >> 6;
  if (lane == 0) {
    red[0][wave] = mse_sum;
    red[1][wave] = am_sum;
    red[2][wave] = val;
    red[3][wave] = has;
  }
  __syncthreads();
  if (threadIdx.x == 0) {
    atomicAdd(&acc[3], red[0][0] + red[0][1] + red[0][2] + red[0][3]);
    atomicAdd(&acc[4], red[1][0] + red[1][1] + red[1][2] + red[1][3]);
    atomicAdd(&acc[5], red[2][0] + red[2][1] + red[2][2] + red[2][3]);
    atomicAdd(&acc[6], red[3][0] + red[3][1] + red[3][2] + red[3][3]);
  }
}

__global__ void finalize_kernel(const float* __restrict__ acc, float* __restrict__ out) {
  float ligand_loss = acc[0] * (1.f / 64.f);
  float ligand_dist_loss = acc[1] / fmaxf(acc[2], 1.f);
  float sidechain_loss = acc[3] / fmaxf(acc[4], 1.f);
  float sidechain_dist_loss = acc[5] / fmaxf(acc[6], 1.f);
  out[0] = 1.0f * ligand_loss + 0.2f * ligand_dist_loss + 0.5f * sidechain_loss +
           0.1f * sidechain_dist_loss;
}

extern "C" void kernel_launch(void* const* d_in, const int* in_sizes, int n_in,
                              void* d_out, int out_size, void* d_ws, size_t ws_size,
                              hipStream_t stream) {
  const float* ligand_pred = (const float*)d_in[0];
  const float* ligand_tgt = (const float*)d_in[1];
  const float* sidechain_pred = (const float*)d_in[2];
  const float* sidechain_tgt = (const float*)d_in[3];
  const int* ligand_mask = (const int*)d_in[4];
  const int* atom_mask = (const int*)d_in[5];
  float* out = (float*)d_out;
  float* acc = (float*)d_ws;

  hipMemsetAsync(acc, 0, 7 * sizeof(float), stream);
  ligand_kernel<<<64, 256, 0, stream>>>(ligand_pred, ligand_tgt, ligand_mask, acc);
  sidechain_kernel<<<256, 256, 0, stream>>>(sidechain_pred, sidechain_tgt, atom_mask, acc);
  finalize_kernel<<<1, 1, 0, stream>>>(acc, out);
}

// Round 2
// 135.361 us; speedup vs baseline: 3.2755x; 3.2755x over previous
//
#include <hip/hip_runtime.h>

#define CUTOFF 5.0f
#define DEPS 1e-12f

// Workspace layout (floats):
// acc[0]              : ligand coord-loss sum of per-batch ratios
// acc[3],acc[4]       : sidechain mse*am sum, am sum
// acc[5],acc[6]       : sidechain dist val sum, has count
// bnum = acc+8  [64]  : per-batch ligand pair num
// bden = acc+72 [64]  : per-batch ligand pair den
// total zeroed: 136 floats

// grid: 64 batches x 16 i-tiles = 1024 blocks, 256 threads
__global__ __launch_bounds__(256) void ligand_kernel(
    const float* __restrict__ pred, const float* __restrict__ tgt,
    const int* __restrict__ mask, float* __restrict__ acc,
    float* __restrict__ bnum, float* __restrict__ bden) {
  const int L = 512;
  const int b = blockIdx.x >> 4;
  const int tile = blockIdx.x & 15;
  const int tid = threadIdx.x;

  __shared__ float sp[512 * 3];
  __shared__ float st[512 * 3];
  __shared__ float sm[512];

  const float4* pb4 = (const float4*)(pred + (size_t)b * L * 3);
  const float4* tb4 = (const float4*)(tgt + (size_t)b * L * 3);
  float4* sp4 = (float4*)sp;
  float4* st4 = (float4*)st;
  for (int i = tid; i < (L * 3) / 4; i += 256) {
    sp4[i] = pb4[i];
    st4[i] = tb4[i];
  }
  for (int i = tid; i < L; i += 256) sm[i] = (mask[(size_t)b * L + i] != 0) ? 1.f : 0.f;
  __syncthreads();

  // coord term: only tile 0 computes it (wave-uniform branch)
  float se = 0.f, cnt = 0.f;
  if (tile == 0) {
    for (int i = tid; i < L; i += 256) {
      float m = sm[i];
      float dx = sp[i * 3 + 0] - st[i * 3 + 0];
      float dy = sp[i * 3 + 1] - st[i * 3 + 1];
      float dz = sp[i * 3 + 2] - st[i * 3 + 2];
      se += m * (dx * dx + dy * dy + dz * dz);
      cnt += m;
    }
  }

  // pair term: full matrix (num & den both double vs i<j -> ratio invariant;
  // diagonal killed by tsq>0). i in [tile*32, tile*32+32), j over 512.
  const int i0 = tile * 32;
  float num = 0.f, den = 0.f;
#pragma unroll 4
  for (int ii = 0; ii < 32; ii++) {
    const int i = i0 + ii;
    const float mi = sm[i];
    const float tix = st[3 * i + 0], tiy = st[3 * i + 1], tiz = st[3 * i + 2];
    const float pix = sp[3 * i + 0], piy = sp[3 * i + 1], piz = sp[3 * i + 2];
#pragma unroll
    for (int half = 0; half < 2; half++) {
      const int j = half * 256 + tid;
      float w = mi * sm[j];
      float dx = tix - st[3 * j + 0];
      float dy = tiy - st[3 * j + 1];
      float dz = tiz - st[3 * j + 2];
      float tsq = dx * dx + dy * dy + dz * dz;
      float td = sqrtf(fmaxf(tsq, DEPS));
      w = (tsq > 0.f) ? w : 0.f;
      w = (td <= CUTOFF) ? w : 0.f;
      float qx = pix - sp[3 * j + 0];
      float qy = piy - sp[3 * j + 1];
      float qz = piz - sp[3 * j + 2];
      float pd = sqrtf(fmaxf(qx * qx + qy * qy + qz * qz, DEPS));
      float d = pd - td;
      num += w * d * d;
      den += w;
    }
  }

  // block reduce 4 values
  for (int off = 32; off > 0; off >>= 1) {
    se += __shfl_down(se, off, 64);
    cnt += __shfl_down(cnt, off, 64);
    num += __shfl_down(num, off, 64);
    den += __shfl_down(den, off, 64);
  }
  __shared__ float red[4][4];
  int lane = tid & 63, wave = tid >> 6;
  if (lane == 0) {
    red[0][wave] = se;
    red[1][wave] = cnt;
    red[2][wave] = num;
    red[3][wave] = den;
  }
  __syncthreads();
  if (tid == 0) {
    float num_t = red[2][0] + red[2][1] + red[2][2] + red[2][3];
    float den_t = red[3][0] + red[3][1] + red[3][2] + red[3][3];
    atomicAdd(&bnum[b], num_t);
    atomicAdd(&bden[b], den_t);
    if (tile == 0) {
      float se_t = red[0][0] + red[0][1] + red[0][2] + red[0][3];
      float cnt_t = red[1][0] + red[1][1] + red[1][2] + red[1][3];
      atomicAdd(&acc[0], se_t / (3.f * fmaxf(cnt_t, 1.f)));
    }
  }
}

// one thread per (b,r) group; branch-free, float2 vector loads
__global__ __launch_bounds__(256) void sidechain_kernel(
    const float* __restrict__ pred, const float* __restrict__ tgt,
    const int* __restrict__ mask, float* __restrict__ acc) {
  const int A = 14;
  const int g = blockIdx.x * 256 + threadIdx.x;  // 65536 groups

  const float2* pg = (const float2*)(pred + (size_t)g * A * 3);
  const float2* tg = (const float2*)(tgt + (size_t)g * A * 3);
  const int2* mg = (const int2*)(mask + (size_t)g * A);

  float2 pbuf[21], tbuf[21];
#pragma unroll
  for (int k = 0; k < 21; k++) {
    pbuf[k] = pg[k];
    tbuf[k] = tg[k];
  }
  int mi_[14];
#pragma unroll
  for (int k = 0; k < 7; k++) {
    int2 v = mg[k];
    mi_[2 * k] = v.x;
    mi_[2 * k + 1] = v.y;
  }
  const float* pf = (const float*)pbuf;
  const float* tf = (const float*)tbuf;

  float m[14], px[14], py[14], pz[14], tx[14], ty[14], tz[14];
  float mse_sum = 0.f, am_sum = 0.f;
#pragma unroll
  for (int a = 0; a < A; a++) {
    m[a] = (mi_[a] != 0) ? 1.f : 0.f;
    px[a] = pf[3 * a + 0];
    py[a] = pf[3 * a + 1];
    pz[a] = pf[3 * a + 2];
    tx[a] = tf[3 * a + 0];
    ty[a] = tf[3 * a + 1];
    tz[a] = tf[3 * a + 2];
    float dx = px[a] - tx[a], dy = py[a] - ty[a], dz = pz[a] - tz[a];
    mse_sum += m[a] * ((dx * dx + dy * dy + dz * dz) * (1.f / 3.f));
    am_sum += m[a];
  }

  float num = 0.f, den = 0.f;
#pragma unroll
  for (int i = 0; i < A; i++) {
#pragma unroll
    for (int j = i + 1; j < A; j++) {
      float w = m[i] * m[j];
      float dx = tx[i] - tx[j], dy = ty[i] - ty[j], dz = tz[i] - tz[j];
      float tsq = dx * dx + dy * dy + dz * dz;
      float td = sqrtf(fmaxf(tsq, DEPS));
      w = (tsq > 0.f) ? w : 0.f;
      w = (td <= CUTOFF) ? w : 0.f;
      float qx = px[i] - px[j], qy = py[i] - py[j], qz = pz[i] - pz[j];
      float pd = sqrtf(fmaxf(qx * qx + qy * qy + qz * qz, DEPS));
      float d = pd - td;
      num += w * d * d;
      den += w;
    }
  }
  float has = (den > 0.f) ? 1.f : 0.f;
  float val = (den > 0.f) ? num / fmaxf(den, 1.f) : 0.f;

  for (int off = 32; off > 0; off >>= 1) {
    mse_sum += __shfl_down(mse_sum, off, 64);
    am_sum += __shfl_down(am_sum, off, 64);
    val += __shfl_down(val, off, 64);
    has += __shfl_down(has, off, 64);
  }
  __shared__ float red[4][4];
  int lane = threadIdx.x & 63, wave = threadIdx.x >> 6;
  if (lane == 0) {
    red[0][wave] = mse_sum;
    red[1][wave] = am_sum;
    red[2][wave] = val;
    red[3][wave] = has;
  }
  __syncthreads();
  if (threadIdx.x == 0) {
    atomicAdd(&acc[3], red[0][0] + red[0][1] + red[0][2] + red[0][3]);
    atomicAdd(&acc[4], red[1][0] + red[1][1] + red[1][2] + red[1][3]);
    atomicAdd(&acc[5], red[2][0] + red[2][1] + red[2][2] + red[2][3]);
    atomicAdd(&acc[6], red[3][0] + red[3][1] + red[3][2] + red[3][3]);
  }
}

__global__ void finalize_kernel(const float* __restrict__ acc,
                                const float* __restrict__ bnum,
                                const float* __restrict__ bden,
                                float* __restrict__ out) {
  int t = threadIdx.x;  // 64 threads = 1 wave, one per batch
  float n = bnum[t], d = bden[t];
  float val = (d > 0.f) ? n / fmaxf(d, 1.f) : 0.f;
  float has = (d > 0.f) ? 1.f : 0.f;
  for (int off = 32; off > 0; off >>= 1) {
    val += __shfl_down(val, off, 64);
    has += __shfl_down(has, off, 64);
  }
  if (t == 0) {
    float ligand_loss = acc[0] * (1.f / 64.f);
    float ligand_dist_loss = val / fmaxf(has, 1.f);
    float sidechain_loss = acc[3] / fmaxf(acc[4], 1.f);
    float sidechain_dist_loss = acc[5] / fmaxf(acc[6], 1.f);
    out[0] = 1.0f * ligand_loss + 0.2f * ligand_dist_loss + 0.5f * sidechain_loss +
             0.1f * sidechain_dist_loss;
  }
}

extern "C" void kernel_launch(void* const* d_in, const int* in_sizes, int n_in,
                              void* d_out, int out_size, void* d_ws, size_t ws_size,
                              hipStream_t stream) {
  const float* ligand_pred = (const float*)d_in[0];
  const float* ligand_tgt = (const float*)d_in[1];
  const float* sidechain_pred = (const float*)d_in[2];
  const float* sidechain_tgt = (const float*)d_in[3];
  const int* ligand_mask = (const int*)d_in[4];
  const int* atom_mask = (const int*)d_in[5];
  float* out = (float*)d_out;
  float* acc = (float*)d_ws;
  float* bnum = acc + 8;
  float* bden = acc + 72;

  hipMemsetAsync(acc, 0, 136 * sizeof(float), stream);
  ligand_kernel<<<1024, 256, 0, stream>>>(ligand_pred, ligand_tgt, ligand_mask, acc, bnum, bden);
  sidechain_kernel<<<256, 256, 0, stream>>>(sidechain_pred, sidechain_tgt, atom_mask, acc);
  finalize_kernel<<<1, 64, 0, stream>>>(acc, bnum, bden, out);
}